// Round 11
// baseline (575.616 us; speedup 1.0000x reference)
//
#include <hip/hip_runtime.h>
#include <hip/hip_bf16.h>

// ---- problem constants ----
#define SEM_DIM   256
#define CODEBOOK  8192
#define B_        8
#define T_        4096
#define D_        292
#define NCH       37
#define EPSV      1e-5f
#define NSP       4            // codebook splits (XCD-pinned via wgid&3)
#define KAPPA     2.05e-3f     // >= 2^-9 deterministic fp16-dot error coeff
#define D0        0.01f        // absolute slack for fp32 epilogue rounding
#define CAP       128

typedef unsigned short u16;
typedef float v4f __attribute__((ext_vector_type(4)));
typedef _Float16 v8h __attribute__((ext_vector_type(8)));

constexpr int ROWS = B_ * T_;                 // 32768
// d_out as flat scratch until final writers run. Scratch spans [0, 7.43M fl);
// finalize/fsq/gather overwrite the full 10.78M-fl output afterwards.
constexpr size_t OFF_XT   = 0;                // fp16[32768*256] = 4,194,304 fl
constexpr size_t OFF_ET   = 4194304;          // fp16[8192*256]  = 1,048,576 fl
constexpr size_t OFF_E2G  = 5242880;          // float2[8192]    = 16,384 fl
constexpr size_t OFF_X2   = 5259264;          // f32[32768]
constexpr size_t OFF_CNT  = 5292032;          // i32[32768]
constexpr size_t OFF_CAND = 5324800;          // u16[32768*128]  = 2,097,152 fl -> 7,421,952
constexpr size_t RECON_OFF = 1212416;

__device__ __forceinline__ u16 h16bits(float v) {
    _Float16 h = (_Float16)v;
    return *(u16*)&h;
}

// ---- kernel 0: init cnt/x2 ----
__global__ __launch_bounds__(256) void init_kernel(int* __restrict__ cnt,
                                                   float* __restrict__ x2)
{
    int r = blockIdx.x * 256 + threadIdx.x;
    cnt[r] = 0;
    x2[r] = 0.f;
}

// ---- kernel 1: Et = fp16(clamp(es/max(cu,eps))) panel-transposed; e2g ----
__global__ __launch_bounds__(256) void prep_emb_kernel(
    const float* __restrict__ es, const float* __restrict__ cu,
    u16* __restrict__ Et, float2* __restrict__ e2g)
{
    int c = blockIdx.x;
    int d = threadIdx.x;
    float denom = fmaxf(cu[c], EPSV);
    float v = es[(size_t)c * SEM_DIM + d] / denom;   // IEEE div, matches ref
    float vc = fminf(fmaxf(v, -60000.f), 60000.f);   // fp16-overflow guard

    __shared__ u16 hbuf[256];
    hbuf[d] = h16bits(vc);

    float s = v * v;
    #pragma unroll
    for (int m = 32; m >= 1; m >>= 1) s += __shfl_xor(s, m);
    __shared__ float red[4];
    int lane = d & 63, w = d >> 6;
    if (lane == 0) red[w] = s;
    __syncthreads();

    if (d < 32) {
        // panel-transposed: byte = (c>>6)*32768 + chunk*1024 + (c&63)*16
        uint4 pk = *(const uint4*)&hbuf[d * 8];
        size_t byt = (size_t)(c >> 6) * 32768 + (size_t)d * 1024 + (size_t)(c & 63) * 16;
        *(uint4*)((char*)Et + byt) = pk;
    }
    if (d == 0) {
        float e2 = red[0] + red[1] + red[2] + red[3];
        e2g[c] = make_float2(e2, KAPPA * sqrtf(e2));
    }
}

// ---- kernel 2: x[:, :256, :] -> Xt (fp16, MFMA-fragment order) + x2 ----
__global__ __launch_bounds__(256) void prep_x_kernel(
    const float* __restrict__ x, u16* __restrict__ Xt, float* __restrict__ x2)
{
    __shared__ float tile[64][65];
    int bidx = blockIdx.x;            // 8 * 64 * 4
    int dc = bidx & 3;
    int tc = (bidx >> 2) & 63;
    int b  = bidx >> 8;
    int d0 = dc * 64, t0 = tc * 64;
    int tx = threadIdx.x & 63;
    int dq = threadIdx.x >> 6;

    float part = 0.f;
    #pragma unroll
    for (int i = 0; i < 16; i++) {
        int d = dq * 16 + i;
        float v = x[((size_t)b * D_ + d0 + d) * T_ + t0 + tx];
        tile[d][tx] = v;
        part = fmaf(v, v, part);
    }
    atomicAdd(&x2[b * T_ + t0 + tx], part);
    __syncthreads();

    #pragma unroll
    for (int j = 0; j < 2; j++) {
        int lin = threadIdx.x * 2 + j;      // 0..511
        int tr  = lin >> 3;
        int ch  = lin & 7;
        unsigned w[4];
        #pragma unroll
        for (int p = 0; p < 4; p++) {
            float v0 = tile[ch * 8 + p * 2 + 0][tr];
            float v1 = tile[ch * 8 + p * 2 + 1][tr];
            w[p] = (unsigned)h16bits(v0) | ((unsigned)h16bits(v1) << 16);
        }
        int row = b * T_ + t0 + tr;
        int R = row >> 4, l15 = row & 15;
        int k8 = d0 / 8 + ch;
        int ks = k8 >> 2, l4 = k8 & 3;
        size_t byt = (size_t)((R * 8 + ks) * 4 + l4) * 256 + (size_t)l15 * 16;
        *(uint4*)((char*)Xt + byt) = make_uint4(w[0], w[1], w[2], w[3]);
    }
}

// ---- kernel 3: fp16 MFMA GEMM, 3-buffer counted-vmcnt pipeline (raw
//      s_barrier, never drains prefetch) + dieted stale-threshold emission ----
#define GBM 256
#define NTT (CODEBOOK / NSP / 32)             // 64 tiles of 32 codes

__global__ __launch_bounds__(256, 2) void gemm_emit_kernel(
    const u16* __restrict__ Xt, const u16* __restrict__ Et,
    const float2* __restrict__ e2g, const float* __restrict__ x2,
    int* __restrict__ cnt, u16* __restrict__ cand)
{
    __shared__ u16 Bs[3][8192];               // 3 x 16 KB tiles (32 codes x 256 K)
    int tid  = threadIdx.x;
    int lane = tid & 63, wid = tid >> 6;      // 4 waves, m64 each
    int l15 = lane & 15, l4 = lane >> 4;
    int mblk = blockIdx.x >> 2, split = blockIdx.x & 3;   // split <-> XCD (mod-4)
    int m0 = mblk * GBM;
    int cbase = split * (CODEBOOK / NSP);

    // A resident: 32 v8h = 128 VGPR (all compile-time indexed)
    v8h aX[4][8];
    #pragma unroll
    for (int mf = 0; mf < 4; mf++) {
        int Rb = (m0 + wid * 64 + mf * 16) >> 4;
        #pragma unroll
        for (int ks = 0; ks < 8; ks++) {
            size_t byt = (size_t)((Rb * 8 + ks) * 4 + l4) * 256 + (size_t)l15 * 16;
            aX[mf][ks] = *(const v8h*)((const char*)Xt + byt);
        }
    }

    float sxv[4][4], rvL[4][4], thr[4][4];
    #pragma unroll
    for (int mf = 0; mf < 4; mf++)
        #pragma unroll
        for (int rr = 0; rr < 4; rr++) {
            int row = m0 + wid * 64 + mf * 16 + l4 * 4 + rr;
            sxv[mf][rr] = sqrtf(x2[row]);
            rvL[mf][rr] = 3.4e38f;
            thr[mf][rr] = 3.4e38f;
        }

    v4f acc[4][2];
    #pragma unroll
    for (int mf = 0; mf < 4; mf++) {
        acc[mf][0] = (v4f){0.f, 0.f, 0.f, 0.f};
        acc[mf][1] = (v4f){0.f, 0.f, 0.f, 0.f};
    }

    // stage tile nt (16 KB): wave-linear dest, per-lane source
    auto stage = [&](int nt, int buf) {
        const char* src = (const char*)Et
            + (size_t)(split * 32 + (nt >> 1)) * 32768 + (size_t)(nt & 1) * 512;
        #pragma unroll
        for (int j = 0; j < 4; j++) {
            int dofs = (wid * 4 + j) * 1024 + lane * 16;
            int q = dofs >> 9;             // chunk 0..31
            int o = (dofs >> 4) & 31;      // code-slot within chunk-half
            __builtin_amdgcn_global_load_lds(
                (const __attribute__((address_space(1))) unsigned*)(src + q * 1024 + o * 16),
                (__attribute__((address_space(3))) unsigned*)((char*)&Bs[buf][0] + dofs),
                16, 0, 0);
        }
    };

    stage(0, 0);
    stage(1, 1);

    for (int t = 0; t < NTT; ++t) {
        // counted wait: oldest (outstanding-4) ops retire -> stage(t) landed;
        // stage(t+1)'s 4 stay in flight across the barrier. Tail drains fully.
        if (t < NTT - 1) asm volatile("s_waitcnt vmcnt(4)" ::: "memory");
        else             asm volatile("s_waitcnt vmcnt(0)" ::: "memory");
        __builtin_amdgcn_s_barrier();
        asm volatile("" ::: "memory");
        if (t + 2 < NTT) stage(t + 2, (t + 2) % 3);   // never drained by barrier

        const char* bp = (const char*)&Bs[t % 3][0];
        #pragma unroll
        for (int ks = 0; ks < 8; ks++) {
            int cofs = (ks * 4 + l4) * 512 + l15 * 16;
            v8h bF0 = *(const v8h*)(bp + cofs);
            v8h bF1 = *(const v8h*)(bp + cofs + 256);
            #pragma unroll
            for (int mf = 0; mf < 4; mf++) {
                acc[mf][0] = __builtin_amdgcn_mfma_f32_16x16x32_f16(
                    aX[mf][ks], bF0, acc[mf][0], 0, 0, 0);
                acc[mf][1] = __builtin_amdgcn_mfma_f32_16x16x32_f16(
                    aX[mf][ks], bF1, acc[mf][1], 0, 0, 0);
            }
        }

        // dieted epilogue: per-lane running min; cross-lane tighten every 4th
        // tile (stale threshold >= row-min-o + D0 always -> coverage holds)
        int c0 = cbase + t * 32;
        float2 eg0 = e2g[c0 + l15];
        float2 eg1 = e2g[c0 + 16 + l15];
        bool tighten = (t & 3) == 0;
        #pragma unroll
        for (int mf = 0; mf < 4; mf++)
            #pragma unroll
            for (int rr = 0; rr < 4; rr++) {
                float sx = sxv[mf][rr];
                float s0 = fmaf(-2.f, acc[mf][0][rr], eg0.x);
                float s1 = fmaf(-2.f, acc[mf][1][rr], eg1.x);
                float o0 = fmaf(sx, eg0.y, s0);
                float o1 = fmaf(sx, eg1.y, s1);
                float rl = fminf(rvL[mf][rr], fminf(o0, o1));
                rvL[mf][rr] = rl;
                if (tighten) {
                    float om = rl;
                    #pragma unroll
                    for (int m = 1; m < 16; m <<= 1)
                        om = fminf(om, __shfl_xor(om, m));
                    thr[mf][rr] = om + D0;
                }
                float th = thr[mf][rr];
                float u0 = fmaf(-sx, eg0.y, s0);
                float u1 = fmaf(-sx, eg1.y, s1);
                if (u0 <= th || u1 <= th) {            // rare
                    int row = m0 + wid * 64 + mf * 16 + l4 * 4 + rr;
                    if (u0 <= th) {
                        int q = atomicAdd(&cnt[row], 1);
                        if (q < CAP) cand[(size_t)row * CAP + q] = (u16)(c0 + l15);
                    }
                    if (u1 <= th) {
                        int q = atomicAdd(&cnt[row], 1);
                        if (q < CAP) cand[(size_t)row * CAP + q] = (u16)(c0 + 16 + l15);
                    }
                }
                acc[mf][0][rr] = 0.f;
                acc[mf][1][rr] = 0.f;
            }
    }
}

// ---- kernel 4: exact fp32 rescore, wave-per-row; wave-parallel full scan
//      on overflow ----
__global__ __launch_bounds__(256) void finalize_kernel(
    const int* __restrict__ cnt, const u16* __restrict__ cand,
    const float* __restrict__ x, const float* __restrict__ es,
    const float* __restrict__ cu, const float2* __restrict__ e2g,
    float* __restrict__ out)
{
    int r = (blockIdx.x * 256 + threadIdx.x) >> 6;   // one wave per row
    int lane = threadIdx.x & 63;
    int b = r >> 12, t = r & 4095;
    int n = cnt[r];

    float xv[4];
    #pragma unroll
    for (int j = 0; j < 4; j++)
        xv[j] = x[((size_t)b * D_ + lane + j * 64) * T_ + t];

    float best_s = 3.4e38f; int best_i = 0x7FFFFFFF;
    if (n <= CAP) {
        for (int p = 0; p < n; p++) {
            int c = (int)cand[(size_t)r * CAP + p];
            float den = fmaxf(cu[c], EPSV);
            float partial = 0.f;
            #pragma unroll
            for (int j = 0; j < 4; j++)
                partial = fmaf(xv[j], es[(size_t)c * SEM_DIM + lane + j * 64] / den, partial);
            #pragma unroll
            for (int m = 32; m >= 1; m >>= 1) partial += __shfl_xor(partial, m);
            float sc = e2g[c].x - 2.0f * partial;
            if (sc < best_s || (sc == best_s && c < best_i)) { best_s = sc; best_i = c; }
        }
    } else {
        // overflow fallback: exact wave-parallel scan of all codes
        for (int c = 0; c < CODEBOOK; c++) {
            float den = fmaxf(cu[c], EPSV);
            float partial = 0.f;
            #pragma unroll
            for (int j = 0; j < 4; j++)
                partial = fmaf(xv[j], es[(size_t)c * SEM_DIM + lane + j * 64] / den, partial);
            #pragma unroll
            for (int m = 32; m >= 1; m <<= 1) partial += __shfl_xor(partial, m);
            float sc = e2g[c].x - 2.0f * partial;
            if (sc < best_s) { best_s = sc; best_i = c; }
        }
    }
    if (lane == 0) out[(size_t)b * NCH * T_ + t] = (float)best_i;
}

// ---- kernel 5: FSQ codes + ac recon ----
__global__ __launch_bounds__(256) void fsq_kernel(
    const float* __restrict__ x, float* __restrict__ out)
{
    int e = blockIdx.x * 256 + threadIdx.x;
    int t = e & 4095;
    int rest = e >> 12;
    int j = rest % 36;
    int b = rest / 36;
    float v = x[(size_t)b * D_ * T_ + (size_t)(SEM_DIM + j) * T_ + t];
    float a = tanhf(v);
    float code = rintf((a + 1.0f) * 10.0f);
    out[(size_t)b * NCH * T_ + (size_t)(1 + j) * T_ + t] = code;
    out[RECON_OFF + (size_t)b * D_ * T_ + (size_t)(SEM_DIM + j) * T_ + t]
        = code * 0.1f - 1.0f;
}

// ---- kernel 6: recon sem gather ----
__global__ __launch_bounds__(256) void gather_kernel(
    const float* __restrict__ es, const float* __restrict__ cu,
    const float* __restrict__ codes, float* __restrict__ out)
{
    int bid = blockIdx.x;
    int b  = bid >> 6;
    int tc = bid & 63;
    int t  = tc * 64 + (threadIdx.x & 63);
    int w  = threadIdx.x >> 6;

    int c = (int)codes[(size_t)b * NCH * T_ + t];
    float denom = fmaxf(cu[c], EPSV);
    const float* erow = es + (size_t)c * SEM_DIM;
    float* orow = out + RECON_OFF + (size_t)b * D_ * T_ + t;

    #pragma unroll
    for (int i = 0; i < 16; i++) {
        int d = w * 64 + i * 4;
        float4 ev = *(const float4*)(erow + d);
        orow[(size_t)(d + 0) * T_] = ev.x / denom;
        orow[(size_t)(d + 1) * T_] = ev.y / denom;
        orow[(size_t)(d + 2) * T_] = ev.z / denom;
        orow[(size_t)(d + 3) * T_] = ev.w / denom;
    }
}

extern "C" void kernel_launch(void* const* d_in, const int* in_sizes, int n_in,
                              void* d_out, int out_size, void* d_ws, size_t ws_size,
                              hipStream_t stream)
{
    const float* x  = (const float*)d_in[0];
    const float* es = (const float*)d_in[1];
    const float* cu = (const float*)d_in[2];
    float* out = (float*)d_out;

    u16*    Xt   = (u16*)(out + OFF_XT);
    u16*    Et   = (u16*)(out + OFF_ET);
    float2* e2g  = (float2*)(out + OFF_E2G);
    float*  x2   = out + OFF_X2;
    int*    cnt  = (int*)(out + OFF_CNT);
    u16*    cand = (u16*)(out + OFF_CAND);

    init_kernel<<<ROWS / 256, 256, 0, stream>>>(cnt, x2);
    prep_emb_kernel<<<CODEBOOK, 256, 0, stream>>>(es, cu, Et, e2g);
    prep_x_kernel<<<B_ * 64 * 4, 256, 0, stream>>>(x, Xt, x2);

    gemm_emit_kernel<<<(ROWS / GBM) * NSP, 256, 0, stream>>>(
        Xt, Et, e2g, x2, cnt, cand);

    finalize_kernel<<<ROWS / 4, 256, 0, stream>>>(cnt, cand, x, es, cu, e2g, out);

    fsq_kernel<<<(B_ * 36 * T_) / 256, 256, 0, stream>>>(x, out);

    gather_kernel<<<B_ * (T_ / 64), 256, 0, stream>>>(es, cu, out, out);
}

// Round 12
// 496.133 us; speedup vs baseline: 1.1602x; 1.1602x over previous
//
#include <hip/hip_runtime.h>
#include <hip/hip_bf16.h>

// ---- problem constants ----
#define SEM_DIM   256
#define CODEBOOK  8192
#define B_        8
#define T_        4096
#define D_        292
#define NCH       37
#define EPSV      1e-5f
#define NSP       4            // codebook splits (XCD-pinned via wgid&3)
#define KAPPA     2.05e-3f     // >= 2^-9 deterministic fp16-dot error coeff
#define D0        0.01f        // absolute slack for fp32 epilogue rounding
#define CAP       128
#define QMAX      1024

typedef unsigned short u16;
typedef float v4f __attribute__((ext_vector_type(4)));
typedef _Float16 v8h __attribute__((ext_vector_type(8)));

constexpr int ROWS = B_ * T_;                 // 32768
// d_out as flat scratch until final writers run. Scratch spans [0, 7.43M fl);
// finalize/fsq/gather overwrite the full 10.78M-fl output afterwards.
constexpr size_t OFF_XT   = 0;                // fp16[32768*256] = 4,194,304 fl
constexpr size_t OFF_ET   = 4194304;          // fp16[8192*256]  = 1,048,576 fl
constexpr size_t OFF_E2G  = 5242880;          // float2[8192]    = 16,384 fl
constexpr size_t OFF_X2   = 5259264;          // f32[32768]
constexpr size_t OFF_CNT  = 5292032;          // i32[32768]
constexpr size_t OFF_CAND = 5324800;          // u16[32768*128]  = 2,097,152 fl -> 7,421,952
constexpr size_t RECON_OFF = 1212416;

__device__ __forceinline__ u16 h16bits(float v) {
    _Float16 h = (_Float16)v;
    return *(u16*)&h;
}

// ---- kernel 0: init cnt/x2 ----
__global__ __launch_bounds__(256) void init_kernel(int* __restrict__ cnt,
                                                   float* __restrict__ x2)
{
    int r = blockIdx.x * 256 + threadIdx.x;
    cnt[r] = 0;
    x2[r] = 0.f;
}

// ---- kernel 1: Et = fp16(clamp(es/max(cu,eps))) panel-transposed; e2g ----
__global__ __launch_bounds__(256) void prep_emb_kernel(
    const float* __restrict__ es, const float* __restrict__ cu,
    u16* __restrict__ Et, float2* __restrict__ e2g)
{
    int c = blockIdx.x;
    int d = threadIdx.x;
    float denom = fmaxf(cu[c], EPSV);
    float v = es[(size_t)c * SEM_DIM + d] / denom;   // IEEE div, matches ref
    float vc = fminf(fmaxf(v, -60000.f), 60000.f);   // fp16-overflow guard

    __shared__ u16 hbuf[256];
    hbuf[d] = h16bits(vc);

    float s = v * v;
    #pragma unroll
    for (int m = 32; m >= 1; m >>= 1) s += __shfl_xor(s, m);
    __shared__ float red[4];
    int lane = d & 63, w = d >> 6;
    if (lane == 0) red[w] = s;
    __syncthreads();

    if (d < 32) {
        // panel-transposed: byte = (c>>6)*32768 + chunk*1024 + (c&63)*16
        uint4 pk = *(const uint4*)&hbuf[d * 8];
        size_t byt = (size_t)(c >> 6) * 32768 + (size_t)d * 1024 + (size_t)(c & 63) * 16;
        *(uint4*)((char*)Et + byt) = pk;
    }
    if (d == 0) {
        float e2 = red[0] + red[1] + red[2] + red[3];
        e2g[c] = make_float2(e2, KAPPA * sqrtf(e2));
    }
}

// ---- kernel 2: x[:, :256, :] -> Xt (fp16, MFMA-fragment order) + x2 ----
__global__ __launch_bounds__(256) void prep_x_kernel(
    const float* __restrict__ x, u16* __restrict__ Xt, float* __restrict__ x2)
{
    __shared__ float tile[64][65];
    int bidx = blockIdx.x;            // 8 * 64 * 4
    int dc = bidx & 3;
    int tc = (bidx >> 2) & 63;
    int b  = bidx >> 8;
    int d0 = dc * 64, t0 = tc * 64;
    int tx = threadIdx.x & 63;
    int dq = threadIdx.x >> 6;

    float part = 0.f;
    #pragma unroll
    for (int i = 0; i < 16; i++) {
        int d = dq * 16 + i;
        float v = x[((size_t)b * D_ + d0 + d) * T_ + t0 + tx];
        tile[d][tx] = v;
        part = fmaf(v, v, part);
    }
    atomicAdd(&x2[b * T_ + t0 + tx], part);
    __syncthreads();

    #pragma unroll
    for (int j = 0; j < 2; j++) {
        int lin = threadIdx.x * 2 + j;      // 0..511
        int tr  = lin >> 3;
        int ch  = lin & 7;
        unsigned w[4];
        #pragma unroll
        for (int p = 0; p < 4; p++) {
            float v0 = tile[ch * 8 + p * 2 + 0][tr];
            float v1 = tile[ch * 8 + p * 2 + 1][tr];
            w[p] = (unsigned)h16bits(v0) | ((unsigned)h16bits(v1) << 16);
        }
        int row = b * T_ + t0 + tr;
        int R = row >> 4, l15 = row & 15;
        int k8 = d0 / 8 + ch;
        int ks = k8 >> 2, l4 = k8 & 3;
        size_t byt = (size_t)((R * 8 + ks) * 4 + l4) * 256 + (size_t)l15 * 16;
        *(uint4*)((char*)Xt + byt) = make_uint4(w[0], w[1], w[2], w[3]);
    }
}

// ---- kernel 3: fp16 MFMA GEMM, m32/wave (high TLP), atomic-free loop:
//      emissions buffered in an LDS queue (lgkm only), e2g prefetched into
//      registers one tile ahead, stage loads the sole vmcnt traffic. ----
#define GBM 128
#define NTT (CODEBOOK / NSP / 32)             // 64 tiles of 32 codes

__global__ __launch_bounds__(256, 3) void gemm_emit_kernel(
    const u16* __restrict__ Xt, const u16* __restrict__ Et,
    const float2* __restrict__ e2g, const float* __restrict__ x2,
    int* __restrict__ cnt, u16* __restrict__ cand)
{
    __shared__ u16 Bs[2][8192];               // 2 x 16 KB tiles (32 codes x 256 K)
    __shared__ unsigned qbuf[QMAX];           // 4 KB emission queue
    __shared__ int qn;
    int tid  = threadIdx.x;
    int lane = tid & 63, wid = tid >> 6;      // 4 waves, m32 each
    int l15 = lane & 15, l4 = lane >> 4;
    int mblk = blockIdx.x >> 2, split = blockIdx.x & 3;   // split <-> XCD (mod-4)
    int m0 = mblk * GBM;
    int cbase = split * (CODEBOOK / NSP);
    if (tid == 0) qn = 0;

    // A resident: 16 v8h = 64 VGPR (all compile-time indexed), rows m0+wid*32
    v8h aX[2][8];
    #pragma unroll
    for (int mf = 0; mf < 2; mf++) {
        int Rb = (m0 + wid * 32 + mf * 16) >> 4;
        #pragma unroll
        for (int ks = 0; ks < 8; ks++) {
            size_t byt = (size_t)((Rb * 8 + ks) * 4 + l4) * 256 + (size_t)l15 * 16;
            aX[mf][ks] = *(const v8h*)((const char*)Xt + byt);
        }
    }

    float sxv[2][4], rvL[2][4];
    #pragma unroll
    for (int mf = 0; mf < 2; mf++)
        #pragma unroll
        for (int rr = 0; rr < 4; rr++) {
            int row = m0 + wid * 32 + mf * 16 + l4 * 4 + rr;
            sxv[mf][rr] = sqrtf(x2[row]);
            rvL[mf][rr] = 3.4e38f;
        }

    v4f acc[2][2];
    #pragma unroll
    for (int mf = 0; mf < 2; mf++) {
        acc[mf][0] = (v4f){0.f, 0.f, 0.f, 0.f};
        acc[mf][1] = (v4f){0.f, 0.f, 0.f, 0.f};
    }

    // stage one 16 KB tile (32 codes x 256 K), wave-linear dest
    auto stage = [&](int nt, int buf) {
        const char* src = (const char*)Et
            + (size_t)(split * 32 + (nt >> 1)) * 32768 + (size_t)(nt & 1) * 512;
        #pragma unroll
        for (int j = 0; j < 4; j++) {
            int dofs = (wid * 4 + j) * 1024 + lane * 16;
            int q = dofs >> 9;
            int o = (dofs >> 4) & 31;
            __builtin_amdgcn_global_load_lds(
                (const __attribute__((address_space(1))) unsigned*)(src + q * 1024 + o * 16),
                (__attribute__((address_space(3))) unsigned*)((char*)&Bs[buf][0] + dofs),
                16, 0, 0);
        }
    };

    // per-tile body: barrier; stage(t+1); prefetch eg(t+1); MFMA; epilogue
    auto body = [&](int t, int buf, const float4& egC, float4& egN) {
        __syncthreads();                       // buf(t) staged & all reads of buf done
        if (t + 1 < NTT) {
            stage(t + 1, buf ^ 1);
            int cn = cbase + (t + 1) * 32;
            float2 a = e2g[cn + l15];
            float2 b = e2g[cn + 16 + l15];
            egN.x = a.x; egN.y = a.y; egN.z = b.x; egN.w = b.y;
        }

        const char* bp = (const char*)&Bs[buf][0];
        #pragma unroll
        for (int ks = 0; ks < 8; ks++) {
            int cofs = (ks * 4 + l4) * 512 + l15 * 16;
            v8h bF0 = *(const v8h*)(bp + cofs);
            v8h bF1 = *(const v8h*)(bp + cofs + 256);
            #pragma unroll
            for (int mf = 0; mf < 2; mf++) {
                acc[mf][0] = __builtin_amdgcn_mfma_f32_16x16x32_f16(
                    aX[mf][ks], bF0, acc[mf][0], 0, 0, 0);
                acc[mf][1] = __builtin_amdgcn_mfma_f32_16x16x32_f16(
                    aX[mf][ks], bF1, acc[mf][1], 0, 0, 0);
            }
        }

        int c0 = cbase + t * 32;
        #pragma unroll
        for (int mf = 0; mf < 2; mf++)
            #pragma unroll
            for (int rr = 0; rr < 4; rr++) {
                float sx = sxv[mf][rr];
                float s0 = fmaf(-2.f, acc[mf][0][rr], egC.x);
                float s1 = fmaf(-2.f, acc[mf][1][rr], egC.z);
                float o0 = fmaf(sx, egC.y, s0);
                float o1 = fmaf(sx, egC.w, s1);
                float om = fminf(o0, o1);
                #pragma unroll
                for (int m = 1; m < 16; m <<= 1)
                    om = fminf(om, __shfl_xor(om, m));
                float rv = fminf(rvL[mf][rr], om);
                rvL[mf][rr] = rv;
                float th = rv + D0;
                float u0 = fmaf(-sx, egC.y, s0);
                float u1 = fmaf(-sx, egC.w, s1);
                if (u0 <= th || u1 <= th) {            // rare
                    int lrow = wid * 32 + mf * 16 + l4 * 4 + rr;
                    if (u0 <= th) {
                        int p = atomicAdd(&qn, 1);
                        unsigned pk = ((unsigned)lrow << 13) | (unsigned)(c0 + l15);
                        if (p < QMAX) qbuf[p] = pk;
                        else {
                            int q = atomicAdd(&cnt[m0 + lrow], 1);
                            if (q < CAP) cand[(size_t)(m0 + lrow) * CAP + q] = (u16)(c0 + l15);
                        }
                    }
                    if (u1 <= th) {
                        int p = atomicAdd(&qn, 1);
                        unsigned pk = ((unsigned)lrow << 13) | (unsigned)(c0 + 16 + l15);
                        if (p < QMAX) qbuf[p] = pk;
                        else {
                            int q = atomicAdd(&cnt[m0 + lrow], 1);
                            if (q < CAP) cand[(size_t)(m0 + lrow) * CAP + q] = (u16)(c0 + 16 + l15);
                        }
                    }
                }
                acc[mf][0][rr] = 0.f;
                acc[mf][1][rr] = 0.f;
            }
    };

    float4 egA, egB;
    stage(0, 0);
    {
        int cn = cbase + l15;
        float2 a = e2g[cn];
        float2 b = e2g[cn + 16];
        egA.x = a.x; egA.y = a.y; egA.z = b.x; egA.w = b.y;
    }

    for (int tp = 0; tp < NTT; tp += 2) {
        body(tp,     0, egA, egB);
        body(tp + 1, 1, egB, egA);
    }

    // flush LDS emission queue to global candidate lists
    __syncthreads();
    int n = qn; if (n > QMAX) n = QMAX;
    for (int i = tid; i < n; i += 256) {
        unsigned pk = qbuf[i];
        int lrow = pk >> 13;
        int code = pk & 8191;
        int row = m0 + lrow;
        int q = atomicAdd(&cnt[row], 1);
        if (q < CAP) cand[(size_t)row * CAP + q] = (u16)code;
    }
}

// ---- kernel 4: exact fp32 rescore, wave-per-row; wave-parallel full scan
//      on overflow ----
__global__ __launch_bounds__(256) void finalize_kernel(
    const int* __restrict__ cnt, const u16* __restrict__ cand,
    const float* __restrict__ x, const float* __restrict__ es,
    const float* __restrict__ cu, const float2* __restrict__ e2g,
    float* __restrict__ out)
{
    int r = (blockIdx.x * 256 + threadIdx.x) >> 6;   // one wave per row
    int lane = threadIdx.x & 63;
    int b = r >> 12, t = r & 4095;
    int n = cnt[r];

    float xv[4];
    #pragma unroll
    for (int j = 0; j < 4; j++)
        xv[j] = x[((size_t)b * D_ + lane + j * 64) * T_ + t];

    float best_s = 3.4e38f; int best_i = 0x7FFFFFFF;
    if (n <= CAP) {
        for (int p = 0; p < n; p++) {
            int c = (int)cand[(size_t)r * CAP + p];
            float den = fmaxf(cu[c], EPSV);
            float partial = 0.f;
            #pragma unroll
            for (int j = 0; j < 4; j++)
                partial = fmaf(xv[j], es[(size_t)c * SEM_DIM + lane + j * 64] / den, partial);
            #pragma unroll
            for (int m = 32; m >= 1; m >>= 1) partial += __shfl_xor(partial, m);
            float sc = e2g[c].x - 2.0f * partial;
            if (sc < best_s || (sc == best_s && c < best_i)) { best_s = sc; best_i = c; }
        }
    } else {
        // overflow fallback: exact wave-parallel scan of all codes
        for (int c = 0; c < CODEBOOK; c++) {
            float den = fmaxf(cu[c], EPSV);
            float partial = 0.f;
            #pragma unroll
            for (int j = 0; j < 4; j++)
                partial = fmaf(xv[j], es[(size_t)c * SEM_DIM + lane + j * 64] / den, partial);
            #pragma unroll
            for (int m = 32; m >= 1; m <<= 1) partial += __shfl_xor(partial, m);
            float sc = e2g[c].x - 2.0f * partial;
            if (sc < best_s) { best_s = sc; best_i = c; }
        }
    }
    if (lane == 0) out[(size_t)b * NCH * T_ + t] = (float)best_i;
}

// ---- kernel 5: FSQ codes + ac recon ----
__global__ __launch_bounds__(256) void fsq_kernel(
    const float* __restrict__ x, float* __restrict__ out)
{
    int e = blockIdx.x * 256 + threadIdx.x;
    int t = e & 4095;
    int rest = e >> 12;
    int j = rest % 36;
    int b = rest / 36;
    float v = x[(size_t)b * D_ * T_ + (size_t)(SEM_DIM + j) * T_ + t];
    float a = tanhf(v);
    float code = rintf((a + 1.0f) * 10.0f);
    out[(size_t)b * NCH * T_ + (size_t)(1 + j) * T_ + t] = code;
    out[RECON_OFF + (size_t)b * D_ * T_ + (size_t)(SEM_DIM + j) * T_ + t]
        = code * 0.1f - 1.0f;
}

// ---- kernel 6: recon sem gather ----
__global__ __launch_bounds__(256) void gather_kernel(
    const float* __restrict__ es, const float* __restrict__ cu,
    const float* __restrict__ codes, float* __restrict__ out)
{
    int bid = blockIdx.x;
    int b  = bid >> 6;
    int tc = bid & 63;
    int t  = tc * 64 + (threadIdx.x & 63);
    int w  = threadIdx.x >> 6;

    int c = (int)codes[(size_t)b * NCH * T_ + t];
    float denom = fmaxf(cu[c], EPSV);
    const float* erow = es + (size_t)c * SEM_DIM;
    float* orow = out + RECON_OFF + (size_t)b * D_ * T_ + t;

    #pragma unroll
    for (int i = 0; i < 16; i++) {
        int d = w * 64 + i * 4;
        float4 ev = *(const float4*)(erow + d);
        orow[(size_t)(d + 0) * T_] = ev.x / denom;
        orow[(size_t)(d + 1) * T_] = ev.y / denom;
        orow[(size_t)(d + 2) * T_] = ev.z / denom;
        orow[(size_t)(d + 3) * T_] = ev.w / denom;
    }
}

extern "C" void kernel_launch(void* const* d_in, const int* in_sizes, int n_in,
                              void* d_out, int out_size, void* d_ws, size_t ws_size,
                              hipStream_t stream)
{
    const float* x  = (const float*)d_in[0];
    const float* es = (const float*)d_in[1];
    const float* cu = (const float*)d_in[2];
    float* out = (float*)d_out;

    u16*    Xt   = (u16*)(out + OFF_XT);
    u16*    Et   = (u16*)(out + OFF_ET);
    float2* e2g  = (float2*)(out + OFF_E2G);
    float*  x2   = out + OFF_X2;
    int*    cnt  = (int*)(out + OFF_CNT);
    u16*    cand = (u16*)(out + OFF_CAND);

    init_kernel<<<ROWS / 256, 256, 0, stream>>>(cnt, x2);
    prep_emb_kernel<<<CODEBOOK, 256, 0, stream>>>(es, cu, Et, e2g);
    prep_x_kernel<<<B_ * 64 * 4, 256, 0, stream>>>(x, Xt, x2);

    gemm_emit_kernel<<<(ROWS / GBM) * NSP, 256, 0, stream>>>(
        Xt, Et, e2g, x2, cnt, cand);

    finalize_kernel<<<ROWS / 4, 256, 0, stream>>>(cnt, cand, x, es, cu, e2g, out);

    fsq_kernel<<<(B_ * 36 * T_) / 256, 256, 0, stream>>>(x, out);

    gather_kernel<<<B_ * (T_ / 64), 256, 0, stream>>>(es, cu, out, out);
}

// Round 13
// 308.640 us; speedup vs baseline: 1.8650x; 1.6075x over previous
//
#include <hip/hip_runtime.h>
#include <hip/hip_bf16.h>

// ---- problem constants ----
#define SEM_DIM   256
#define CODEBOOK  8192
#define B_        8
#define T_        4096
#define D_        292
#define NCH       37
#define EPSV      1e-5f
#define NSP       4            // codebook splits
#define KAPPA     2.05e-3f     // >= 2^-9 deterministic fp16-dot error coeff
#define D0        0.01f        // absolute slack for fp32 epilogue rounding
#define CAP       128
#define QMAX      1536

typedef unsigned short u16;
typedef float v4f __attribute__((ext_vector_type(4)));
typedef _Float16 v8h __attribute__((ext_vector_type(8)));

constexpr int ROWS = B_ * T_;                 // 32768
// d_out as flat scratch until final writers run. Scratch spans [0, 7.43M fl);
// finalize/fsq/gather overwrite the full 10.78M-fl output afterwards.
constexpr size_t OFF_XT   = 0;                // fp16[32768*256] = 4,194,304 fl
constexpr size_t OFF_ET   = 4194304;          // fp16[8192*256]  = 1,048,576 fl
constexpr size_t OFF_E2G  = 5242880;          // e2f[8192] + gf[8192]
constexpr size_t OFF_X2   = 5259264;          // f32[32768]
constexpr size_t OFF_CNT  = 5292032;          // i32[32768]
constexpr size_t OFF_CAND = 5324800;          // u16[32768*128] -> 7,421,952
constexpr size_t RECON_OFF = 1212416;

__device__ __forceinline__ u16 h16bits(float v) {
    _Float16 h = (_Float16)v;
    return *(u16*)&h;
}

// ---- kernel 0: init cnt/x2 ----
__global__ __launch_bounds__(256) void init_kernel(int* __restrict__ cnt,
                                                   float* __restrict__ x2)
{
    int r = blockIdx.x * 256 + threadIdx.x;
    cnt[r] = 0;
    x2[r] = 0.f;
}

// ---- kernel 1: Et = fp16(clamp(es/max(cu,eps))) panel-transposed; e2f/gf ----
__global__ __launch_bounds__(256) void prep_emb_kernel(
    const float* __restrict__ es, const float* __restrict__ cu,
    u16* __restrict__ Et, float* __restrict__ e2f, float* __restrict__ gf)
{
    int c = blockIdx.x;
    int d = threadIdx.x;
    float denom = fmaxf(cu[c], EPSV);
    float v = es[(size_t)c * SEM_DIM + d] / denom;   // IEEE div, matches ref
    float vc = fminf(fmaxf(v, -60000.f), 60000.f);   // fp16-overflow guard

    __shared__ u16 hbuf[256];
    hbuf[d] = h16bits(vc);

    float s = v * v;
    #pragma unroll
    for (int m = 32; m >= 1; m >>= 1) s += __shfl_xor(s, m);
    __shared__ float red[4];
    int lane = d & 63, w = d >> 6;
    if (lane == 0) red[w] = s;
    __syncthreads();

    if (d < 32) {
        // panel-transposed: byte = (c>>6)*32768 + chunk*1024 + (c&63)*16
        uint4 pk = *(const uint4*)&hbuf[d * 8];
        size_t byt = (size_t)(c >> 6) * 32768 + (size_t)d * 1024 + (size_t)(c & 63) * 16;
        *(uint4*)((char*)Et + byt) = pk;
    }
    if (d == 0) {
        float e2 = red[0] + red[1] + red[2] + red[3];
        e2f[c] = e2;
        gf[c]  = KAPPA * sqrtf(e2);
    }
}

// ---- kernel 2: x[:, :256, :] -> Xt (fp16, MFMA-fragment order) + x2 ----
__global__ __launch_bounds__(256) void prep_x_kernel(
    const float* __restrict__ x, u16* __restrict__ Xt, float* __restrict__ x2)
{
    __shared__ float tile[64][65];
    int bidx = blockIdx.x;            // 8 * 64 * 4
    int dc = bidx & 3;
    int tc = (bidx >> 2) & 63;
    int b  = bidx >> 8;
    int d0 = dc * 64, t0 = tc * 64;
    int tx = threadIdx.x & 63;
    int dq = threadIdx.x >> 6;

    float part = 0.f;
    #pragma unroll
    for (int i = 0; i < 16; i++) {
        int d = dq * 16 + i;
        float v = x[((size_t)b * D_ + d0 + d) * T_ + t0 + tx];
        tile[d][tx] = v;
        part = fmaf(v, v, part);
    }
    atomicAdd(&x2[b * T_ + t0 + tx], part);
    __syncthreads();

    #pragma unroll
    for (int j = 0; j < 2; j++) {
        int lin = threadIdx.x * 2 + j;      // 0..511
        int tr  = lin >> 3;
        int ch  = lin & 7;
        unsigned w[4];
        #pragma unroll
        for (int p = 0; p < 4; p++) {
            float v0 = tile[ch * 8 + p * 2 + 0][tr];
            float v1 = tile[ch * 8 + p * 2 + 1][tr];
            w[p] = (unsigned)h16bits(v0) | ((unsigned)h16bits(v1) << 16);
        }
        int row = b * T_ + t0 + tr;
        int R = row >> 4, l15 = row & 15;
        int k8 = d0 / 8 + ch;
        int ks = k8 >> 2, l4 = k8 & 3;
        size_t byt = (size_t)((R * 8 + ks) * 4 + l4) * 256 + (size_t)l15 * 16;
        *(uint4*)((char*)Xt + byt) = make_uint4(w[0], w[1], w[2], w[3]);
    }
}

// ---- kernel 3: fp16 MFMA GEMM, swapped operands (codes on D-row axis ->
//      lane-local 8-code min, 2 shfls/row), 8-wave blocks (4 waves/SIMD),
//      LDS-staged e2/g tables, LDS emission queue. ----
#define GBM 256
#define NTT (CODEBOOK / NSP / 32)             // 64 tiles of 32 codes

__global__ __launch_bounds__(512, 4) void gemm_emit_kernel(
    const u16* __restrict__ Xt, const u16* __restrict__ Et,
    const float* __restrict__ e2f, const float* __restrict__ gf,
    const float* __restrict__ x2,
    int* __restrict__ cnt, u16* __restrict__ cand)
{
    __shared__ u16 Bs[2][8192];               // 2 x 16 KB code tiles
    __shared__ float e2s[2048], gs[2048];     // split-local score tables
    __shared__ unsigned qbuf[QMAX];
    __shared__ int qn;
    int tid  = threadIdx.x;
    int lane = tid & 63, wid = tid >> 6;      // 8 waves, m32 each
    int l15 = lane & 15, l4 = lane >> 4;
    int mblk = blockIdx.x >> 2, split = blockIdx.x & 3;
    int m0 = mblk * GBM;
    int cbase = split * (CODEBOOK / NSP);
    if (tid == 0) qn = 0;

    // stage e2/g tables once (512 thr x 4 floats each)
    {
        int c4 = tid * 4;
        *(float4*)&e2s[c4] = *(const float4*)&e2f[cbase + c4];
        *(float4*)&gs[c4]  = *(const float4*)&gf[cbase + c4];
    }

    // x fragments resident (B-operand): m = m0 + wid*32 + mfm*16 + l15
    v8h aX[2][8];
    #pragma unroll
    for (int mfm = 0; mfm < 2; mfm++) {
        int Rb = (m0 + wid * 32 + mfm * 16) >> 4;
        #pragma unroll
        for (int ks = 0; ks < 8; ks++) {
            size_t byt = (size_t)((Rb * 8 + ks) * 4 + l4) * 256 + (size_t)l15 * 16;
            aX[mfm][ks] = *(const v8h*)((const char*)Xt + byt);
        }
    }

    float sxv[2], rvL[2];
    #pragma unroll
    for (int mfm = 0; mfm < 2; mfm++) {
        sxv[mfm] = sqrtf(x2[m0 + wid * 32 + mfm * 16 + l15]);
        rvL[mfm] = 3.4e38f;
    }

    v4f acc[2][2];                            // [mfc(code-half)][mfm(m-half)]
    #pragma unroll
    for (int a = 0; a < 2; a++)
        #pragma unroll
        for (int b = 0; b < 2; b++)
            acc[a][b] = (v4f){0.f, 0.f, 0.f, 0.f};

    // stage one 16 KB tile (32 codes x 256 K): 512 thr x 2 x 16B
    auto stage = [&](int nt, int buf) {
        const char* src = (const char*)Et
            + (size_t)(split * 32 + (nt >> 1)) * 32768 + (size_t)(nt & 1) * 512;
        #pragma unroll
        for (int j = 0; j < 2; j++) {
            int dofs = wid * 2048 + j * 1024 + lane * 16;
            int q = dofs >> 9;
            int o = (dofs >> 4) & 31;
            __builtin_amdgcn_global_load_lds(
                (const __attribute__((address_space(1))) unsigned*)(src + q * 1024 + o * 16),
                (__attribute__((address_space(3))) unsigned*)((char*)&Bs[buf][0] + dofs),
                16, 0, 0);
        }
    };

    stage(0, 0);

    for (int t = 0; t < NTT; ++t) {
        int buf = t & 1;
        __syncthreads();                      // stage(t) landed; prev reads done
        if (t + 1 < NTT) stage(t + 1, buf ^ 1);

        const char* bp = (const char*)&Bs[buf][0];
        #pragma unroll
        for (int ks = 0; ks < 8; ks++) {
            int cofs = (ks * 4 + l4) * 512 + l15 * 16;
            v8h bC0 = *(const v8h*)(bp + cofs);
            v8h bC1 = *(const v8h*)(bp + cofs + 256);
            #pragma unroll
            for (int mfm = 0; mfm < 2; mfm++) {
                acc[0][mfm] = __builtin_amdgcn_mfma_f32_16x16x32_f16(
                    bC0, aX[mfm][ks], acc[0][mfm], 0, 0, 0);
                acc[1][mfm] = __builtin_amdgcn_mfma_f32_16x16x32_f16(
                    bC1, aX[mfm][ks], acc[1][mfm], 0, 0, 0);
            }
        }

        // epilogue: lane owns codes c0 + mfc*16 + l4*4 + rr for m-col l15
        int c0  = cbase + t * 32;
        int clb = t * 32 + l4 * 4;
        float4 e2q0 = *(const float4*)&e2s[clb];
        float4 e2q1 = *(const float4*)&e2s[clb + 16];
        float4 gq0  = *(const float4*)&gs[clb];
        float4 gq1  = *(const float4*)&gs[clb + 16];
        float e2a[2][4] = {{e2q0.x, e2q0.y, e2q0.z, e2q0.w},
                           {e2q1.x, e2q1.y, e2q1.z, e2q1.w}};
        float ga[2][4]  = {{gq0.x, gq0.y, gq0.z, gq0.w},
                           {gq1.x, gq1.y, gq1.z, gq1.w}};

        #pragma unroll
        for (int mfm = 0; mfm < 2; mfm++) {
            float sx = sxv[mfm];
            float om = 3.4e38f;
            float u[2][4];
            #pragma unroll
            for (int mfc = 0; mfc < 2; mfc++)
                #pragma unroll
                for (int rr = 0; rr < 4; rr++) {
                    float s = fmaf(-2.f, acc[mfc][mfm][rr], e2a[mfc][rr]);
                    om = fminf(om, fmaf(sx, ga[mfc][rr], s));
                    u[mfc][rr] = fmaf(-sx, ga[mfc][rr], s);
                }
            om = fminf(om, __shfl_xor(om, 16));
            om = fminf(om, __shfl_xor(om, 32));
            float rv = fminf(rvL[mfm], om);
            rvL[mfm] = rv;
            float th = rv + D0;
            int lrow = wid * 32 + mfm * 16 + l15;
            #pragma unroll
            for (int mfc = 0; mfc < 2; mfc++)
                #pragma unroll
                for (int rr = 0; rr < 4; rr++) {
                    if (u[mfc][rr] <= th) {   // rare
                        unsigned pk = ((unsigned)lrow << 13)
                                    | (unsigned)(c0 + mfc * 16 + l4 * 4 + rr);
                        int p = atomicAdd(&qn, 1);
                        if (p < QMAX) qbuf[p] = pk;
                        else {
                            int row = m0 + lrow;
                            int q = atomicAdd(&cnt[row], 1);
                            if (q < CAP) cand[(size_t)row * CAP + q] = (u16)(pk & 8191);
                        }
                    }
                }
        }
        #pragma unroll
        for (int a = 0; a < 2; a++)
            #pragma unroll
            for (int b = 0; b < 2; b++)
                acc[a][b] = (v4f){0.f, 0.f, 0.f, 0.f};
    }

    // flush LDS emission queue to global candidate lists
    __syncthreads();
    int n = qn; if (n > QMAX) n = QMAX;
    for (int i = tid; i < n; i += 512) {
        unsigned pk = qbuf[i];
        int row = m0 + (pk >> 13);
        int q = atomicAdd(&cnt[row], 1);
        if (q < CAP) cand[(size_t)row * CAP + q] = (u16)(pk & 8191);
    }
}

// ---- kernel 4: exact fp32 rescore, wave-per-row; wave-parallel full scan
//      on overflow ----
__global__ __launch_bounds__(256) void finalize_kernel(
    const int* __restrict__ cnt, const u16* __restrict__ cand,
    const float* __restrict__ x, const float* __restrict__ es,
    const float* __restrict__ cu, const float* __restrict__ e2f,
    float* __restrict__ out)
{
    int r = (blockIdx.x * 256 + threadIdx.x) >> 6;   // one wave per row
    int lane = threadIdx.x & 63;
    int b = r >> 12, t = r & 4095;
    int n = cnt[r];

    float xv[4];
    #pragma unroll
    for (int j = 0; j < 4; j++)
        xv[j] = x[((size_t)b * D_ + lane + j * 64) * T_ + t];

    float best_s = 3.4e38f; int best_i = 0x7FFFFFFF;
    if (n <= CAP) {
        for (int p = 0; p < n; p++) {
            int c = (int)cand[(size_t)r * CAP + p];
            float den = fmaxf(cu[c], EPSV);
            float partial = 0.f;
            #pragma unroll
            for (int j = 0; j < 4; j++)
                partial = fmaf(xv[j], es[(size_t)c * SEM_DIM + lane + j * 64] / den, partial);
            #pragma unroll
            for (int m = 32; m >= 1; m >>= 1) partial += __shfl_xor(partial, m);
            float sc = e2f[c] - 2.0f * partial;
            if (sc < best_s || (sc == best_s && c < best_i)) { best_s = sc; best_i = c; }
        }
    } else {
        // overflow fallback: exact wave-parallel scan of all codes
        for (int c = 0; c < CODEBOOK; c++) {
            float den = fmaxf(cu[c], EPSV);
            float partial = 0.f;
            #pragma unroll
            for (int j = 0; j < 4; j++)
                partial = fmaf(xv[j], es[(size_t)c * SEM_DIM + lane + j * 64] / den, partial);
            #pragma unroll
            for (int m = 32; m >= 1; m <<= 1) partial += __shfl_xor(partial, m);
            float sc = e2f[c] - 2.0f * partial;
            if (sc < best_s) { best_s = sc; best_i = c; }
        }
    }
    if (lane == 0) out[(size_t)b * NCH * T_ + t] = (float)best_i;
}

// ---- kernel 5: FSQ codes + ac recon ----
__global__ __launch_bounds__(256) void fsq_kernel(
    const float* __restrict__ x, float* __restrict__ out)
{
    int e = blockIdx.x * 256 + threadIdx.x;
    int t = e & 4095;
    int rest = e >> 12;
    int j = rest % 36;
    int b = rest / 36;
    float v = x[(size_t)b * D_ * T_ + (size_t)(SEM_DIM + j) * T_ + t];
    float a = tanhf(v);
    float code = rintf((a + 1.0f) * 10.0f);
    out[(size_t)b * NCH * T_ + (size_t)(1 + j) * T_ + t] = code;
    out[RECON_OFF + (size_t)b * D_ * T_ + (size_t)(SEM_DIM + j) * T_ + t]
        = code * 0.1f - 1.0f;
}

// ---- kernel 6: recon sem gather ----
__global__ __launch_bounds__(256) void gather_kernel(
    const float* __restrict__ es, const float* __restrict__ cu,
    const float* __restrict__ codes, float* __restrict__ out)
{
    int bid = blockIdx.x;
    int b  = bid >> 6;
    int tc = bid & 63;
    int t  = tc * 64 + (threadIdx.x & 63);
    int w  = threadIdx.x >> 6;

    int c = (int)codes[(size_t)b * NCH * T_ + t];
    float denom = fmaxf(cu[c], EPSV);
    const float* erow = es + (size_t)c * SEM_DIM;
    float* orow = out + RECON_OFF + (size_t)b * D_ * T_ + t;

    #pragma unroll
    for (int i = 0; i < 16; i++) {
        int d = w * 64 + i * 4;
        float4 ev = *(const float4*)(erow + d);
        orow[(size_t)(d + 0) * T_] = ev.x / denom;
        orow[(size_t)(d + 1) * T_] = ev.y / denom;
        orow[(size_t)(d + 2) * T_] = ev.z / denom;
        orow[(size_t)(d + 3) * T_] = ev.w / denom;
    }
}

extern "C" void kernel_launch(void* const* d_in, const int* in_sizes, int n_in,
                              void* d_out, int out_size, void* d_ws, size_t ws_size,
                              hipStream_t stream)
{
    const float* x  = (const float*)d_in[0];
    const float* es = (const float*)d_in[1];
    const float* cu = (const float*)d_in[2];
    float* out = (float*)d_out;

    u16*   Xt   = (u16*)(out + OFF_XT);
    u16*   Et   = (u16*)(out + OFF_ET);
    float* e2f  = out + OFF_E2G;
    float* gf   = out + OFF_E2G + 8192;
    float* x2   = out + OFF_X2;
    int*   cnt  = (int*)(out + OFF_CNT);
    u16*   cand = (u16*)(out + OFF_CAND);

    init_kernel<<<ROWS / 256, 256, 0, stream>>>(cnt, x2);
    prep_emb_kernel<<<CODEBOOK, 256, 0, stream>>>(es, cu, Et, e2f, gf);
    prep_x_kernel<<<B_ * 64 * 4, 256, 0, stream>>>(x, Xt, x2);

    gemm_emit_kernel<<<(ROWS / GBM) * NSP, 512, 0, stream>>>(
        Xt, Et, e2f, gf, x2, cnt, cand);

    finalize_kernel<<<ROWS / 4, 256, 0, stream>>>(cnt, cand, x, es, cu, e2f, out);

    fsq_kernel<<<(B_ * 36 * T_) / 256, 256, 0, stream>>>(x, out);

    gather_kernel<<<B_ * (T_ / 64), 256, 0, stream>>>(es, cu, out, out);
}